// Round 10
// baseline (30580.240 us; speedup 1.0000x reference)
//
#include <hip/hip_runtime.h>
#include <hip/hip_cooperative_groups.h>
#include <cmath>

namespace cg = cooperative_groups;

#define TSEQ 2048
#define H    1024
#define L    4
#define WPL  64          // workgroups per layer
#define NWG  (WPL * L)   // 256 blocks = 1 per CU
#define NTH  512         // 8 waves per block
#define NBUF 4           // h ring depth (power of 2)

typedef unsigned u32;
typedef unsigned long long u64;

__device__ __forceinline__ float waveSum(float v) {
#pragma unroll
  for (int off = 32; off > 0; off >>= 1) v += __shfl_xor(v, off, 64);
  return v;
}

__device__ __forceinline__ float sigmoidf_(float x) {
  return 1.0f / (1.0f + __expf(-x));
}

__device__ __forceinline__ unsigned bf16rne(float f) {
  unsigned u = __float_as_uint(f);
  return (u + 0x7fffu + ((u >> 16) & 1u)) >> 16;
}

__device__ __forceinline__ u64 ldU64(const u64* p) {
  return __hip_atomic_load(p, __ATOMIC_RELAXED, __HIP_MEMORY_SCOPE_AGENT);
}
__device__ __forceinline__ void stU64(u64* p, u64 v) {
  __hip_atomic_store(p, v, __ATOMIC_RELAXED, __HIP_MEMORY_SCOPE_AGENT);
}

// Persistent-register-weight LSTM; sync via STAMPED h WORDS: every h element
// is published as one 8B atomic {stamp:32 | fp32:32}. The store IS the
// notification; the consumer's stamp-spin IS the data load. One MALL round
// trip per step replaces round-9's publish -> notify -> observe -> load.
//   hline[b][l][r] : ring slot b = t & 3, layer l, row r. stamp = t+1.
// Consumer block (l,*) at step t, thread tid (owns rows 2tid,2tid+1 slices):
//   own  : hline[(t-1)&3][l]  [2tid..]   stamp >= t      (h_l(t-1))
//   below: hline[ t   &3][l-1][2tid..]   stamp >= t+1    (h_{l-1}(t))  [l>0]
//   WAR  : wave0 lane i: hline[t&3][l+1][16i] stamp >= t-3 (layer l+1
//          finished step t-4, so slot t&3 may be overwritten)  [l<3, t>=4]
// Skew-aliasing safety: a peer can only publish stamp t+4 into our own-read
// slot after ALL peers (incl. us) finished t+2; we are mid-t. Below-slot
// overwrite (stamp t+5) requires layer-(l-1) WAR gate: us >= t. Both safe.
// hline is touched ONLY by agent-scope atomics (incl. zero-init).
__global__ __launch_bounds__(NTH, 2) void lstm_seq(
    const float* __restrict__ X,                                   // [TSEQ][H]
    const float* __restrict__ Uf,  const float* __restrict__ Ug,   // [H][H]
    const float* __restrict__ Uq,  const float* __restrict__ Uc,
    const float* __restrict__ UHf, const float* __restrict__ UHg,  // [L-1][H][H]
    const float* __restrict__ UHq, const float* __restrict__ UHc,
    const float* __restrict__ Wf,  const float* __restrict__ Wg,   // [L][H][H]
    const float* __restrict__ Wq,  const float* __restrict__ Wc,
    const float* __restrict__ Bf,  const float* __restrict__ Bg,   // [L][H]
    const float* __restrict__ Bq,  const float* __restrict__ Bc,
    u64*   __restrict__ hline,  // ws: [NBUF][L][H] stamped h words
    float* __restrict__ out)    // [L][H]
{
  cg::grid_group grid = cg::this_grid();
  const int tid  = threadIdx.x;
  const int lane = tid & 63;
  const int wv   = tid >> 6;            // wave 0..7
  const int l    = blockIdx.x >> 6;     // layer 0..3
  const int wgl  = blockIdx.x & 63;     // block index within layer
  const int r0   = wgl * 16 + wv * 2;   // this wave's 2 output rows

  // d_ws poisoned 0xAA before every call: zero the stamped ring (atomics!)
  {
    const int gtid = blockIdx.x * NTH + tid;
    for (int i = gtid; i < NBUF * L * H; i += NWG * NTH) stU64(&hline[i], 0ull);
  }

  // ---- matrix pointers: 0..3 = W-side (recurrent), 4..7 = U-side ----------
  const size_t lHH = (size_t)l * H * H;
  const float* Mp[8];
  Mp[0] = Wf + lHH; Mp[1] = Wg + lHH; Mp[2] = Wq + lHH; Mp[3] = Wc + lHH;
  if (l == 0) {
    Mp[4] = Uf; Mp[5] = Ug; Mp[6] = Uq; Mp[7] = Uc;
  } else {
    const size_t o = (size_t)(l - 1) * H * H;
    Mp[4] = UHf + o; Mp[5] = UHg + o; Mp[6] = UHq + o; Mp[7] = UHc + o;
  }

  // ---- one-time weight fetch -> bf16x2 packed registers (128 regs) --------
  // wpk[mi][ri][q] holds cols {2*lane+128q (lo), +1 (hi)} of row r0+ri.
  unsigned wpk[8][2][8];
#pragma unroll
  for (int mi = 0; mi < 8; ++mi)
#pragma unroll
    for (int ri = 0; ri < 2; ++ri) {
      const float* rowp = Mp[mi] + (size_t)(r0 + ri) * H + 2 * lane;
#pragma unroll
      for (int q = 0; q < 8; ++q) {
        float2 w2 = *(const float2*)(rowp + 128 * q);
        wpk[mi][ri][q] = bf16rne(w2.x) | (bf16rne(w2.y) << 16);
      }
    }

  float bias[4][2];
#pragma unroll
  for (int ri = 0; ri < 2; ++ri) {
    bias[0][ri] = Bf[(size_t)l * H + r0 + ri];
    bias[1][ri] = Bg[(size_t)l * H + r0 + ri];
    bias[2][ri] = Bq[(size_t)l * H + r0 + ri];
    bias[3][ri] = Bc[(size_t)l * H + r0 + ri];
  }

  float sreg[2] = {0.0f, 0.0f};  // cell state for this wave's 2 rows

  __shared__ alignas(16) float hAsh[H];  // own h(t-1)
  __shared__ alignas(16) float hBsh[H];  // layer-0: x_t ; else h_below(t)

  __threadfence();
  grid.sync();   // one-time: zero-init visible everywhere

  for (int t = 0; t < TSEQ; ++t) {
    const u32 tu = (u32)t;

    // ---- acquire fragments: spin directly on stamped data words ----------
    const u64* ownp = hline + ((size_t)((t - 1) & (NBUF - 1)) * L + l) * H + 2 * tid;
    u64 a0, a1, b0, b1;
    float2 xv;
    if (l == 0) xv = *(const float2*)(X + (size_t)t * H + 2 * tid);
    if (l == 0) {
      for (;;) {
        a0 = ldU64(ownp); a1 = ldU64(ownp + 1);
        if (((u32)(a0 >> 32) >= tu) & ((u32)(a1 >> 32) >= tu)) break;
        __builtin_amdgcn_s_sleep(1);
      }
    } else {
      const u64* belp = hline + ((size_t)(t & (NBUF - 1)) * L + (l - 1)) * H + 2 * tid;
      for (;;) {
        a0 = ldU64(ownp); a1 = ldU64(ownp + 1);
        b0 = ldU64(belp); b1 = ldU64(belp + 1);
        bool ok = ((u32)(a0 >> 32) >= tu) & ((u32)(a1 >> 32) >= tu) &
                  ((u32)(b0 >> 32) >= tu + 1) & ((u32)(b1 >> 32) >= tu + 1);
        if (ok) break;
        __builtin_amdgcn_s_sleep(1);
      }
    }
    ((float2*)hAsh)[tid] = make_float2(__uint_as_float((u32)a0),
                                       __uint_as_float((u32)a1));
    ((float2*)hBsh)[tid] = (l == 0)
        ? xv
        : make_float2(__uint_as_float((u32)b0), __uint_as_float((u32)b1));

    // ---- WAR gate: slot t&3 may be overwritten when layer l+1 >= t-3 -----
    if (wv == 0 && l < L - 1 && t >= NBUF) {
      const u64* wp = hline + ((size_t)(t & (NBUF - 1)) * L + (l + 1)) * H + 16 * lane;
      for (;;) {
        bool c = ((u32)(ldU64(wp) >> 32) >= tu - 3);
        if (__all(c)) break;
        __builtin_amdgcn_s_sleep(2);
      }
    }
    __syncthreads();

    // ---- per-lane slices from LDS (conflict-free b64 pattern) ------------
    float ha[16], hb[16];
#pragma unroll
    for (int q = 0; q < 8; ++q) {
      u64 va = ((const u64*)hAsh)[lane + 64 * q];
      ha[2 * q]     = __uint_as_float((u32)va);
      ha[2 * q + 1] = __uint_as_float((u32)(va >> 32));
      u64 vb = ((const u64*)hBsh)[lane + 64 * q];
      hb[2 * q]     = __uint_as_float((u32)vb);
      hb[2 * q + 1] = __uint_as_float((u32)(vb >> 32));
    }

    float acc[4][2];
#pragma unroll
    for (int g = 0; g < 4; ++g)
#pragma unroll
      for (int ri = 0; ri < 2; ++ri) {
        float a = 0.0f;
#pragma unroll
        for (int q = 0; q < 8; ++q) {
          const unsigned wA = wpk[g][ri][q];         // W-side (recurrent)
          a = fmaf(__uint_as_float(wA << 16),         ha[2 * q],     a);
          a = fmaf(__uint_as_float(wA & 0xffff0000u), ha[2 * q + 1], a);
          const unsigned wB = wpk[4 + g][ri][q];     // U-side (input/below)
          a = fmaf(__uint_as_float(wB << 16),         hb[2 * q],     a);
          a = fmaf(__uint_as_float(wB & 0xffff0000u), hb[2 * q + 1], a);
        }
        acc[g][ri] = a;
      }

#pragma unroll
    for (int g = 0; g < 4; ++g)
#pragma unroll
      for (int ri = 0; ri < 2; ++ri) acc[g][ri] = waveSum(acc[g][ri]);

    float hN[2];
#pragma unroll
    for (int ri = 0; ri < 2; ++ri) {
      float f  = sigmoidf_(bias[0][ri] + acc[0][ri]);
      float g_ = sigmoidf_(bias[1][ri] + acc[1][ri]);
      float q_ = sigmoidf_(bias[2][ri] + acc[2][ri]);
      float cd = sigmoidf_(bias[3][ri] + acc[3][ri]);
      float sN = f * sreg[ri] + g_ * cd;
      sreg[ri] = sN;
      hN[ri] = tanhf(sN) * q_;
    }
    // publish: stamped words, store = data + notification in one shot
    if (lane == 0) {
      u64* dst = hline + ((size_t)(t & (NBUF - 1)) * L + l) * H + r0;
      const u64 st = (u64)(tu + 1) << 32;
      stU64(dst,     st | (u64)__float_as_uint(hN[0]));
      stU64(dst + 1, st | (u64)__float_as_uint(hN[1]));
      if (t == TSEQ - 1) {
        out[(size_t)l * H + r0]     = hN[0];
        out[(size_t)l * H + r0 + 1] = hN[1];
      }
    }
    __syncthreads();  // LDS WAR: all waves done reading hAsh/hBsh this step
  }
}

// ---------------- launch ----------------------------------------------------
extern "C" void kernel_launch(void* const* d_in, const int* in_sizes, int n_in,
                              void* d_out, int out_size, void* d_ws, size_t ws_size,
                              hipStream_t stream) {
  const float* x   = (const float*)d_in[0];
  const float* Uf  = (const float*)d_in[1];
  const float* UHf = (const float*)d_in[2];
  const float* Wf  = (const float*)d_in[3];
  const float* Bf  = (const float*)d_in[4];
  const float* Ug  = (const float*)d_in[5];
  const float* UHg = (const float*)d_in[6];
  const float* Wg  = (const float*)d_in[7];
  const float* Bg  = (const float*)d_in[8];
  const float* Uq  = (const float*)d_in[9];
  const float* UHq = (const float*)d_in[10];
  const float* Wq  = (const float*)d_in[11];
  const float* Bq  = (const float*)d_in[12];
  const float* Uc  = (const float*)d_in[13];
  const float* UHc = (const float*)d_in[14];
  const float* Wc  = (const float*)d_in[15];
  const float* Bc  = (const float*)d_in[16];
  float* out = (float*)d_out;

  u64* hline = (u64*)d_ws;  // [NBUF][L][H] u64 = 128 KB

  void* args[] = { (void*)&x,
                   (void*)&Uf, (void*)&Ug, (void*)&Uq, (void*)&Uc,
                   (void*)&UHf, (void*)&UHg, (void*)&UHq, (void*)&UHc,
                   (void*)&Wf, (void*)&Wg, (void*)&Wq, (void*)&Wc,
                   (void*)&Bf, (void*)&Bg, (void*)&Bq, (void*)&Bc,
                   (void*)&hline, (void*)&out };
  hipLaunchCooperativeKernel(reinterpret_cast<void*>(lstm_seq),
                             dim3(NWG), dim3(NTH), args, 0, stream);
}